// Round 6
// baseline (22.390 us; speedup 1.0000x reference)
//
#include <hip/hip_runtime.h>
#include <math.h>

#define NB   16
#define NA   5
#define NC   20
#define NG   32
#define HWSZ 4096
#define WDIM 64
#define NCH  25          // 5 + NC
#define OBJ_SCALE 5.0f
#define NBLK ((NB * NA * HWSZ) / 256)   // 1280

// ---- shared device body: per-(b,a,cell) loss; returns block partial in wsum ----
__device__ __forceinline__ float yolo_block_partial(
    const float* __restrict__ output,
    const float* __restrict__ target,
    const void*  __restrict__ gt_valid_raw,
    const float* __restrict__ anchors,
    float* wsum /* __shared__ [4] */)
{
    __shared__ float4 sbox[NG];   // gt corners x1,y1,x2,y2 (degenerate if invalid)
    __shared__ float2 sthr[NG];   // x: 0.375*garea, y: cell if (valid && best==a) else -1
    __shared__ float  sga [NG];   // gt area
    __shared__ float  stx [NG], sty[NG], stw[NG], sth2[NG], scls[NG];

    int tid  = threadIdx.x;
    int idx  = blockIdx.x * 256 + tid;
    int b    = idx / (NA * HWSZ);      // uniform per block (20480 % 256 == 0)
    int rem  = idx % (NA * HWSZ);
    int a    = rem / HWSZ;             // uniform per block
    int cell = rem % HWSZ;

    // --- wave-0 prep: dtype sniff via ballot (no barriers), then per-gt fields
    if (tid < 64) {
        const unsigned char* bytes = (const unsigned char*)gt_valid_raw;
        // Sniff gt_valid dtype from first 256 bytes (in-bounds for u8 512B,
        // i32/f32 2048B). u8 bool -> nonzero bytes at (i&3)==1 positions;
        // f32 1.0f (00 00 80 3F) -> nonzero only at (i&3)>=2; i32 1 -> only ==0.
        unsigned char bb = bytes[tid] | bytes[tid + 64] | bytes[tid + 128] | bytes[tid + 192];
        unsigned long long m = __ballot(bb != 0);
        bool is_u8  = (m & 0x2222222222222222ULL) != 0ULL;
        bool is_f32 = !is_u8 && (m & 0xCCCCCCCCCCCCCCCCULL) != 0ULL;

        if (tid < NG) {
            int t = b * NG + tid;
            bool valid;
            if (is_u8)       valid = bytes[t] != 0;
            else if (is_f32) valid = ((const float*)gt_valid_raw)[t] != 0.0f;
            else             valid = ((const int*)gt_valid_raw)[t]   != 0;

            const float* tg = target + t * 5;
            float x = tg[0], y = tg[1], w = tg[2], h = tg[3], cls = tg[4];
            const float inv = 1.0f / 32.0f;
            float gx = (x + 0.5f * w) * inv;
            float gy = (y + 0.5f * h) * inv;
            float gw = w * inv, gh = h * inv;
            float garea = gw * gh;

            // best anchor: IOU of (0,0,gw,gh) vs (0,0,aw,ah); first-max wins
            int best = 0; float bi = -1.0f, baw = 1.0f, bah = 1.0f;
            #pragma unroll
            for (int n = 0; n < NA; ++n) {
                float aw_ = anchors[2*n], ah_ = anchors[2*n + 1];
                float inter = fminf(gw, aw_) * fminf(gh, ah_);
                float iou   = inter / (garea + aw_ * ah_ - inter);
                if (iou > bi) { bi = iou; best = n; baw = aw_; bah = ah_; }
            }
            int gi = min(max((int)gx, 0), WDIM - 1);
            int gj = min(max((int)gy, 0), WDIM - 1);

            if (valid) {
                sbox[tid] = make_float4(gx - 0.5f*gw, gy - 0.5f*gh,
                                        gx + 0.5f*gw, gy + 0.5f*gh);
                sthr[tid] = make_float2(0.375f * garea,
                                        (best == a) ? (float)(gj * WDIM + gi) : -1.0f);
            } else {
                sbox[tid] = make_float4(1e30f, 1e30f, -1e30f, -1e30f); // never overlaps
                sthr[tid] = make_float2(0.0f, -1.0f);                  // never matches
            }
            sga [tid] = garea;
            stx [tid] = gx - (float)gi;
            sty [tid] = gy - (float)gj;
            stw [tid] = logf(fmaxf(gw, 1.0f) / baw);
            sth2[tid] = logf(fmaxf(gh, 1.0f) / bah);
            scls[tid] = cls;
        }
    }
    __syncthreads();

    const float* base = output + ((size_t)(b * NA + a) * NCH) * HWSZ + cell;
    float ox = base[0];
    float oy = base[1 * HWSZ];
    float ow = base[2 * HWSZ];
    float oh = base[3 * HWSZ];
    float oc = base[4 * HWSZ];

    float sx   = 1.0f / (1.0f + __expf(-ox));
    float sy   = 1.0f / (1.0f + __expf(-oy));
    float conf = 1.0f / (1.0f + __expf(-oc));
    float pw = __expf(ow) * anchors[2 * a];
    float ph = __expf(oh) * anchors[2 * a + 1];
    float px = sx + (float)(cell & (WDIM - 1));
    float py = sy + (float)(cell >> 6);
    float px1 = px - 0.5f * pw, px2 = px + 0.5f * pw;
    float py1 = py - 0.5f * ph, py2 = py + 0.5f * ph;
    float parea = pw * ph;

    float negc1 = -0.375f * parea;     // inter/union>0.6 <=> inter-0.375*pa > 0.375*ga
    float cellf = (float)cell;
    bool  ignore = false;
    int   match  = -1;                 // last matching g wins (numpy scatter semantics)
    #pragma unroll
    for (int g = 0; g < NG; ++g) {
        float4 bx = sbox[g];
        float2 tc = sthr[g];
        float dx = fminf(px2, bx.z) - fmaxf(px1, bx.x);
        float dy = fminf(py2, bx.w) - fmaxf(py1, bx.y);
        dx = fmaxf(dx, 0.0f); dy = fmaxf(dy, 0.0f);
        ignore |= (fmaf(dx, dy, negc1) > tc.x);
        if (tc.y == cellf) match = g;
    }

    float lsum  = 0.0f;
    float cm    = ignore ? 0.0f : 1.0f;   // NOOBJECT_SCALE = 1
    float tconf = 0.0f;
    if (match >= 0) {
        cm = OBJ_SCALE;
        // exact IOU for the matched gt (one real division, rare threads only)
        float4 bx = sbox[match];
        float dx = fmaxf(fminf(px2, bx.z) - fmaxf(px1, bx.x), 0.0f);
        float dy = fmaxf(fminf(py2, bx.w) - fmaxf(py1, bx.y), 0.0f);
        float inter = dx * dy;
        tconf = inter / (parea + sga[match] - inter);
        // coord loss (COORD_SCALE = 1)
        float d0 = sx - stx [match];
        float d1 = sy - sty [match];
        float d2 = ow - stw [match];
        float d3 = oh - sth2[match];
        lsum += d0*d0 + d1*d1 + d2*d2 + d3*d3;
        // class CE (CLASS_SCALE * 2)
        int tcl = (int)scls[match];
        float lg[NC];
        float m = -1e30f, ltgt = 0.0f;
        #pragma unroll
        for (int c = 0; c < NC; ++c) {     // static indexing only
            lg[c] = base[(5 + c) * HWSZ];
            m = fmaxf(m, lg[c]);
            if (c == tcl) ltgt = lg[c];
        }
        float se = 0.0f;
        #pragma unroll
        for (int c = 0; c < NC; ++c) se += __expf(lg[c] - m);
        float ce = -(ltgt - m - __logf(se));
        lsum += 2.0f * ce;
    }
    float dc = conf - tconf;
    lsum += cm * dc * dc;

    // block reduction: 64-lane shfl, 4 waves via LDS
    #pragma unroll
    for (int off = 32; off > 0; off >>= 1) lsum += __shfl_down(lsum, off);
    int lane = tid & 63, wid = tid >> 6;
    if (lane == 0) wsum[wid] = lsum;
    __syncthreads();
    return wsum[0] + wsum[1] + wsum[2] + wsum[3];   // valid in all threads
}

// ---- fused single-dispatch kernel: decoupled flags, block NBLK-1 reduces ----
__global__ __launch_bounds__(256, 5) void yolo_loss_fused(
    const float* __restrict__ output,
    const float* __restrict__ target,
    const void*  __restrict__ gt_valid_raw,
    const float* __restrict__ anchors,
    float* __restrict__ partials,
    unsigned int* __restrict__ flags,
    float* __restrict__ out)
{
    __shared__ float wsum[4];
    float bs = yolo_block_partial(output, target, gt_valid_raw, anchors, wsum);

    int tid = threadIdx.x;
    if (tid == 0) {
        __hip_atomic_store(&partials[blockIdx.x], bs,
                           __ATOMIC_RELAXED, __HIP_MEMORY_SCOPE_AGENT);
        __hip_atomic_store(&flags[blockIdx.x], 1u,
                           __ATOMIC_RELEASE, __HIP_MEMORY_SCOPE_AGENT);
    }

    if (blockIdx.x != NBLK - 1) return;

    // consumer: spin-acquire each flag (all 1280 blocks are co-resident:
    // 5 blocks/CU x 4 waves = 20 <= 32 waves/CU), fixed-order deterministic sum
    float s = 0.0f;
    #pragma unroll
    for (int k = 0; k < NBLK / 256; ++k) {
        int i = k * 256 + tid;
        while (__hip_atomic_load(&flags[i], __ATOMIC_ACQUIRE,
                                 __HIP_MEMORY_SCOPE_AGENT) != 1u) {
            __builtin_amdgcn_s_sleep(2);
        }
        s += __hip_atomic_load(&partials[i], __ATOMIC_RELAXED,
                               __HIP_MEMORY_SCOPE_AGENT);
        // reset for the next replay (kernel boundary orders this vs next set)
        __hip_atomic_store(&flags[i], 0u, __ATOMIC_RELAXED,
                           __HIP_MEMORY_SCOPE_AGENT);
    }
    #pragma unroll
    for (int off = 32; off > 0; off >>= 1) s += __shfl_down(s, off);
    int lane = tid & 63, wid = tid >> 6;
    if (lane == 0) wsum[wid] = s;
    __syncthreads();
    if (tid == 0) out[0] = (wsum[0] + wsum[1] + wsum[2] + wsum[3]) * (1.0f / 16.0f);
}

// ---- fallback: proven 2-dispatch path (used only if ws is tiny) ----
__global__ __launch_bounds__(256) void yolo_loss2(
    const float* __restrict__ output, const float* __restrict__ target,
    const void*  __restrict__ gt_valid_raw, const float* __restrict__ anchors,
    float* __restrict__ partials)
{
    __shared__ float wsum[4];
    float bs = yolo_block_partial(output, target, gt_valid_raw, anchors, wsum);
    if (threadIdx.x == 0) partials[blockIdx.x] = bs;
}

__global__ __launch_bounds__(256) void yolo_reduce(const float* __restrict__ partials,
                                                   float* __restrict__ out)
{
    int tid = threadIdx.x;
    float s = 0.0f;
    #pragma unroll
    for (int i = 0; i < NBLK / 256; ++i) s += partials[i * 256 + tid];
    #pragma unroll
    for (int off = 32; off > 0; off >>= 1) s += __shfl_down(s, off);
    __shared__ float wsum[4];
    int lane = tid & 63, wid = tid >> 6;
    if (lane == 0) wsum[wid] = s;
    __syncthreads();
    if (tid == 0) out[0] = (wsum[0] + wsum[1] + wsum[2] + wsum[3]) * (1.0f / 16.0f);
}

extern "C" void kernel_launch(void* const* d_in, const int* in_sizes, int n_in,
                              void* d_out, int out_size, void* d_ws, size_t ws_size,
                              hipStream_t stream) {
    const float* output   = (const float*)d_in[0];
    const float* target   = (const float*)d_in[1];
    const void*  gt_valid = d_in[2];
    const float* anchors  = (const float*)d_in[3];
    float* out = (float*)d_out;

    if (ws_size >= NBLK * (sizeof(float) + sizeof(unsigned int))) {
        float*        partials = (float*)d_ws;
        unsigned int* flags    = (unsigned int*)((char*)d_ws + NBLK * sizeof(float));
        yolo_loss_fused<<<NBLK, 256, 0, stream>>>(output, target, gt_valid, anchors,
                                                  partials, flags, out);
    } else {
        float* partials = (float*)d_ws;   // requires >= 5 KB; always true in practice
        yolo_loss2<<<NBLK, 256, 0, stream>>>(output, target, gt_valid, anchors, partials);
        yolo_reduce<<<1, 256, 0, stream>>>(partials, out);
    }
}

// Round 7
// 17.887 us; speedup vs baseline: 1.2518x; 1.2518x over previous
//
#include <hip/hip_runtime.h>
#include <math.h>

#define NB   16
#define NA   5
#define NC   20
#define NG   32
#define HWSZ 4096
#define WDIM 64
#define NCH  25          // 5 + NC
#define OBJ_SCALE 5.0f
#define CPT  2                                   // cells per thread
#define NBLK ((NB * NA * HWSZ) / (256 * CPT))    // 640
#define BPT  (NBLK / NB)                         // 40 blocks per batch
#define BPA  (BPT / NA)                          // 8 blocks per (b,a) tile

// One thread per 2 adjacent cells of one (b,a) tile. Wave-0 lanes 0..31
// redundantly compute per-gt prep into LDS; all 256 threads run the div-free
// ignore/match loop for both cells; block partial -> partials[blockIdx].
__global__ __launch_bounds__(256) void yolo_loss2(
    const float* __restrict__ output,
    const float* __restrict__ target,
    const void*  __restrict__ gt_valid_raw,
    const float* __restrict__ anchors,
    float* __restrict__ partials)
{
    __shared__ float4 sbox[NG];   // gt corners x1,y1,x2,y2 (degenerate if invalid)
    __shared__ float2 sthr[NG];   // x: 0.375*garea, y: cell if (valid && best==a) else -1
    __shared__ float  sga [NG];   // gt area
    __shared__ float  stx [NG], sty[NG], stw[NG], sth2[NG], scls[NG];
    __shared__ float  wsum[4];

    int tid   = threadIdx.x;
    int blk   = blockIdx.x;
    int b     = blk / BPT;                   // uniform per block
    int r     = blk % BPT;
    int a     = r / BPA;                     // uniform per block
    int cell0 = (r % BPA) * (256 * CPT) + tid * CPT;

    // --- wave-0 prep: dtype sniff via ballot (no barriers), then per-gt fields
    if (tid < 64) {
        const unsigned char* bytes = (const unsigned char*)gt_valid_raw;
        // Sniff gt_valid dtype from first 256 bytes (in-bounds for u8 512B,
        // i32/f32 2048B). u8 bool -> nonzero bytes at (i&3)==1 positions;
        // f32 1.0f (00 00 80 3F) -> nonzero only at (i&3)>=2; i32 1 -> only ==0.
        unsigned char bb = bytes[tid] | bytes[tid + 64] | bytes[tid + 128] | bytes[tid + 192];
        unsigned long long m = __ballot(bb != 0);
        bool is_u8  = (m & 0x2222222222222222ULL) != 0ULL;
        bool is_f32 = !is_u8 && (m & 0xCCCCCCCCCCCCCCCCULL) != 0ULL;

        if (tid < NG) {
            int t = b * NG + tid;
            bool valid;
            if (is_u8)       valid = bytes[t] != 0;
            else if (is_f32) valid = ((const float*)gt_valid_raw)[t] != 0.0f;
            else             valid = ((const int*)gt_valid_raw)[t]   != 0;

            const float* tg = target + t * 5;
            float x = tg[0], y = tg[1], w = tg[2], h = tg[3], cls = tg[4];
            const float inv = 1.0f / 32.0f;
            float gx = (x + 0.5f * w) * inv;
            float gy = (y + 0.5f * h) * inv;
            float gw = w * inv, gh = h * inv;
            float garea = gw * gh;

            // best anchor: IOU of (0,0,gw,gh) vs (0,0,aw,ah); first-max wins
            int best = 0; float bi = -1.0f, baw = 1.0f, bah = 1.0f;
            #pragma unroll
            for (int n = 0; n < NA; ++n) {
                float aw_ = anchors[2*n], ah_ = anchors[2*n + 1];
                float inter = fminf(gw, aw_) * fminf(gh, ah_);
                float iou   = inter / (garea + aw_ * ah_ - inter);
                if (iou > bi) { bi = iou; best = n; baw = aw_; bah = ah_; }
            }
            int gi = min(max((int)gx, 0), WDIM - 1);
            int gj = min(max((int)gy, 0), WDIM - 1);

            if (valid) {
                sbox[tid] = make_float4(gx - 0.5f*gw, gy - 0.5f*gh,
                                        gx + 0.5f*gw, gy + 0.5f*gh);
                sthr[tid] = make_float2(0.375f * garea,
                                        (best == a) ? (float)(gj * WDIM + gi) : -1.0f);
            } else {
                sbox[tid] = make_float4(1e30f, 1e30f, -1e30f, -1e30f); // never overlaps
                sthr[tid] = make_float2(0.0f, -1.0f);                  // never matches
            }
            sga [tid] = garea;
            stx [tid] = gx - (float)gi;
            sty [tid] = gy - (float)gj;
            stw [tid] = logf(fmaxf(gw, 1.0f) / baw);
            sth2[tid] = logf(fmaxf(gh, 1.0f) / bah);
            scls[tid] = cls;
        }
    }
    __syncthreads();

    const float* base = output + ((size_t)(b * NA + a) * NCH) * HWSZ + cell0;
    // vectorized channel loads: 2 adjacent cells per thread (8B aligned)
    float2 v0 = *(const float2*)&base[0];
    float2 v1 = *(const float2*)&base[1 * HWSZ];
    float2 v2 = *(const float2*)&base[2 * HWSZ];
    float2 v3 = *(const float2*)&base[3 * HWSZ];
    float2 v4 = *(const float2*)&base[4 * HWSZ];

    float ox[CPT]    = { v0.x, v0.y };
    float oy[CPT]    = { v1.x, v1.y };
    float ow[CPT]    = { v2.x, v2.y };
    float oh[CPT]    = { v3.x, v3.y };
    float oc[CPT]    = { v4.x, v4.y };

    float sx[CPT], sy[CPT], conf[CPT];
    float px1[CPT], px2[CPT], py1[CPT], py2[CPT], parea[CPT], negc1[CPT], cellf[CPT];
    bool  ignore[CPT];
    int   match[CPT];

    float anw = anchors[2 * a], anh = anchors[2 * a + 1];
    #pragma unroll
    for (int j = 0; j < CPT; ++j) {
        int cell = cell0 + j;
        sx[j]   = 1.0f / (1.0f + __expf(-ox[j]));
        sy[j]   = 1.0f / (1.0f + __expf(-oy[j]));
        conf[j] = 1.0f / (1.0f + __expf(-oc[j]));
        float pw = __expf(ow[j]) * anw;
        float ph = __expf(oh[j]) * anh;
        float px = sx[j] + (float)(cell & (WDIM - 1));
        float py = sy[j] + (float)(cell >> 6);
        px1[j] = px - 0.5f * pw;  px2[j] = px + 0.5f * pw;
        py1[j] = py - 0.5f * ph;  py2[j] = py + 0.5f * ph;
        parea[j] = pw * ph;
        negc1[j] = -0.375f * parea[j];   // iou>0.6 <=> inter-0.375*pa > 0.375*ga
        cellf[j] = (float)cell;
        ignore[j] = false;
        match[j]  = -1;                  // last matching g wins (numpy semantics)
    }

    #pragma unroll
    for (int g = 0; g < NG; ++g) {
        float4 bx = sbox[g];
        float2 tc = sthr[g];
        #pragma unroll
        for (int j = 0; j < CPT; ++j) {
            float dx = fminf(px2[j], bx.z) - fmaxf(px1[j], bx.x);
            float dy = fminf(py2[j], bx.w) - fmaxf(py1[j], bx.y);
            dx = fmaxf(dx, 0.0f); dy = fmaxf(dy, 0.0f);
            ignore[j] |= (fmaf(dx, dy, negc1[j]) > tc.x);
            if (tc.y == cellf[j]) match[j] = g;
        }
    }

    float lsum = 0.0f;
    #pragma unroll
    for (int j = 0; j < CPT; ++j) {
        float cm    = ignore[j] ? 0.0f : 1.0f;   // NOOBJECT_SCALE = 1
        float tconf = 0.0f;
        if (match[j] >= 0) {
            int mg = match[j];
            cm = OBJ_SCALE;
            // exact IOU for the matched gt (rare threads only)
            float4 bx = sbox[mg];
            float dx = fmaxf(fminf(px2[j], bx.z) - fmaxf(px1[j], bx.x), 0.0f);
            float dy = fmaxf(fminf(py2[j], bx.w) - fmaxf(py1[j], bx.y), 0.0f);
            float inter = dx * dy;
            tconf = inter / (parea[j] + sga[mg] - inter);
            // coord loss (COORD_SCALE = 1)
            float d0 = sx[j] - stx [mg];
            float d1 = sy[j] - sty [mg];
            float d2 = ow[j] - stw [mg];
            float d3 = oh[j] - sth2[mg];
            lsum += d0*d0 + d1*d1 + d2*d2 + d3*d3;
            // class CE (CLASS_SCALE * 2)
            int tcl = (int)scls[mg];
            float lg[NC];
            float m = -1e30f, ltgt = 0.0f;
            #pragma unroll
            for (int c = 0; c < NC; ++c) {     // static indexing only
                lg[c] = base[(5 + c) * HWSZ + j];
                m = fmaxf(m, lg[c]);
                if (c == tcl) ltgt = lg[c];
            }
            float se = 0.0f;
            #pragma unroll
            for (int c = 0; c < NC; ++c) se += __expf(lg[c] - m);
            float ce = -(ltgt - m - __logf(se));
            lsum += 2.0f * ce;
        }
        float dc = conf[j] - tconf;
        lsum += cm * dc * dc;
    }

    // block reduction: 64-lane shfl, 4 waves via LDS
    #pragma unroll
    for (int off = 32; off > 0; off >>= 1) lsum += __shfl_down(lsum, off);
    int lane = tid & 63, wid = tid >> 6;
    if (lane == 0) wsum[wid] = lsum;
    __syncthreads();
    if (tid == 0) partials[blockIdx.x] = wsum[0] + wsum[1] + wsum[2] + wsum[3];
}

// Tree-reduce the 640 block partials -> out[0]. One block, deterministic.
__global__ __launch_bounds__(256) void yolo_reduce(const float* __restrict__ partials,
                                                   float* __restrict__ out)
{
    int tid = threadIdx.x;
    float s = 0.0f;
    #pragma unroll
    for (int i = 0; i < (NBLK + 255) / 256; ++i) {
        int k = i * 256 + tid;
        if (k < NBLK) s += partials[k];
    }
    #pragma unroll
    for (int off = 32; off > 0; off >>= 1) s += __shfl_down(s, off);
    __shared__ float wsum[4];
    int lane = tid & 63, wid = tid >> 6;
    if (lane == 0) wsum[wid] = s;
    __syncthreads();
    if (tid == 0) out[0] = (wsum[0] + wsum[1] + wsum[2] + wsum[3]) * (1.0f / 16.0f);
}

extern "C" void kernel_launch(void* const* d_in, const int* in_sizes, int n_in,
                              void* d_out, int out_size, void* d_ws, size_t ws_size,
                              hipStream_t stream) {
    const float* output   = (const float*)d_in[0];
    const float* target   = (const float*)d_in[1];
    const void*  gt_valid = d_in[2];
    const float* anchors  = (const float*)d_in[3];
    float* out      = (float*)d_out;
    float* partials = (float*)d_ws;    // needs 2560 B; ws is ample

    yolo_loss2<<<NBLK, 256, 0, stream>>>(output, target, gt_valid, anchors, partials);
    yolo_reduce<<<1, 256, 0, stream>>>(partials, out);
}

// Round 8
// 15.815 us; speedup vs baseline: 1.4158x; 1.1310x over previous
//
#include <hip/hip_runtime.h>
#include <math.h>

#define NB   16
#define NA   5
#define NC   20
#define NG   32
#define HWSZ 4096
#define WDIM 64
#define NCH  25          // 5 + NC
#define OBJ_SCALE 5.0f
#define NBLK ((NB * NA * HWSZ) / 256)   // 1280 = exactly 5 blocks/CU (balanced)

// One thread per (b,a,cell). Wave-0 lanes 0..31 redundantly compute per-gt
// prep for this block's (batch, anchor) into LDS; all 256 threads run a
// div-free ignore/match loop; block partial -> partials[blockIdx] (no atomic).
__global__ __launch_bounds__(256) void yolo_loss(
    const float* __restrict__ output,
    const float* __restrict__ target,
    const void*  __restrict__ gt_valid_raw,
    const float* __restrict__ anchors,
    float* __restrict__ partials)
{
    __shared__ float4 sbox[NG];   // gt corners x1,y1,x2,y2 (degenerate if invalid)
    __shared__ float2 sthr[NG];   // x: 0.375*garea, y: cell if (valid && best==a) else -1
    __shared__ float  sga [NG];   // gt area
    __shared__ float  stx [NG], sty[NG], stw[NG], sth2[NG], scls[NG];
    __shared__ float  wsum[4];

    int tid  = threadIdx.x;
    int idx  = blockIdx.x * 256 + tid;
    int b    = idx / (NA * HWSZ);      // uniform per block (20480 % 256 == 0)
    int rem  = idx % (NA * HWSZ);
    int a    = rem / HWSZ;             // uniform per block
    int cell = rem % HWSZ;

    // --- wave-0 prep: dtype sniff via ballot (no barriers), then per-gt fields
    if (tid < 64) {
        const unsigned char* bytes = (const unsigned char*)gt_valid_raw;
        // Sniff gt_valid dtype from first 256 bytes (in-bounds for u8 512B,
        // i32/f32 2048B). u8 bool -> nonzero bytes at (i&3)==1 positions;
        // f32 1.0f (00 00 80 3F) -> nonzero only at (i&3)>=2; i32 1 -> only ==0.
        unsigned char bb = bytes[tid] | bytes[tid + 64] | bytes[tid + 128] | bytes[tid + 192];
        unsigned long long m = __ballot(bb != 0);
        bool is_u8  = (m & 0x2222222222222222ULL) != 0ULL;
        bool is_f32 = !is_u8 && (m & 0xCCCCCCCCCCCCCCCCULL) != 0ULL;

        if (tid < NG) {
            int t = b * NG + tid;
            bool valid;
            if (is_u8)       valid = bytes[t] != 0;
            else if (is_f32) valid = ((const float*)gt_valid_raw)[t] != 0.0f;
            else             valid = ((const int*)gt_valid_raw)[t]   != 0;

            const float* tg = target + t * 5;
            float x = tg[0], y = tg[1], w = tg[2], h = tg[3], cls = tg[4];
            const float inv = 1.0f / 32.0f;
            float gx = (x + 0.5f * w) * inv;
            float gy = (y + 0.5f * h) * inv;
            float gw = w * inv, gh = h * inv;
            float garea = gw * gh;

            // best anchor: IOU of (0,0,gw,gh) vs (0,0,aw,ah); first-max wins
            int best = 0; float bi = -1.0f, baw = 1.0f, bah = 1.0f;
            #pragma unroll
            for (int n = 0; n < NA; ++n) {
                float aw_ = anchors[2*n], ah_ = anchors[2*n + 1];
                float inter = fminf(gw, aw_) * fminf(gh, ah_);
                float iou   = inter / (garea + aw_ * ah_ - inter);
                if (iou > bi) { bi = iou; best = n; baw = aw_; bah = ah_; }
            }
            int gi = min(max((int)gx, 0), WDIM - 1);
            int gj = min(max((int)gy, 0), WDIM - 1);

            if (valid) {
                sbox[tid] = make_float4(gx - 0.5f*gw, gy - 0.5f*gh,
                                        gx + 0.5f*gw, gy + 0.5f*gh);
                sthr[tid] = make_float2(0.375f * garea,
                                        (best == a) ? (float)(gj * WDIM + gi) : -1.0f);
            } else {
                sbox[tid] = make_float4(1e30f, 1e30f, -1e30f, -1e30f); // never overlaps
                sthr[tid] = make_float2(0.0f, -1.0f);                  // never matches
            }
            sga [tid] = garea;
            stx [tid] = gx - (float)gi;
            sty [tid] = gy - (float)gj;
            stw [tid] = logf(fmaxf(gw, 1.0f) / baw);
            sth2[tid] = logf(fmaxf(gh, 1.0f) / bah);
            scls[tid] = cls;
        }
    }
    __syncthreads();

    const float* base = output + ((size_t)(b * NA + a) * NCH) * HWSZ + cell;
    float ox = base[0];
    float oy = base[1 * HWSZ];
    float ow = base[2 * HWSZ];
    float oh = base[3 * HWSZ];
    float oc = base[4 * HWSZ];

    float sx   = 1.0f / (1.0f + __expf(-ox));
    float sy   = 1.0f / (1.0f + __expf(-oy));
    float conf = 1.0f / (1.0f + __expf(-oc));
    float pw = __expf(ow) * anchors[2 * a];
    float ph = __expf(oh) * anchors[2 * a + 1];
    float px = sx + (float)(cell & (WDIM - 1));
    float py = sy + (float)(cell >> 6);
    float px1 = px - 0.5f * pw, px2 = px + 0.5f * pw;
    float py1 = py - 0.5f * ph, py2 = py + 0.5f * ph;
    float parea = pw * ph;

    float negc1 = -0.375f * parea;     // inter/union>0.6 <=> inter-0.375*pa > 0.375*ga
    float cellf = (float)cell;
    bool  ignore = false;
    int   match  = -1;                 // last matching g wins (numpy scatter semantics)
    #pragma unroll
    for (int g = 0; g < NG; ++g) {
        float4 bx = sbox[g];
        float2 tc = sthr[g];
        float dx = fminf(px2, bx.z) - fmaxf(px1, bx.x);
        float dy = fminf(py2, bx.w) - fmaxf(py1, bx.y);
        dx = fmaxf(dx, 0.0f); dy = fmaxf(dy, 0.0f);
        ignore |= (fmaf(dx, dy, negc1) > tc.x);
        if (tc.y == cellf) match = g;
    }

    float lsum  = 0.0f;
    float cm    = ignore ? 0.0f : 1.0f;   // NOOBJECT_SCALE = 1
    float tconf = 0.0f;
    if (match >= 0) {
        cm = OBJ_SCALE;
        // exact IOU for the matched gt (one real division, rare threads only)
        float4 bx = sbox[match];
        float dx = fmaxf(fminf(px2, bx.z) - fmaxf(px1, bx.x), 0.0f);
        float dy = fmaxf(fminf(py2, bx.w) - fmaxf(py1, bx.y), 0.0f);
        float inter = dx * dy;
        tconf = inter / (parea + sga[match] - inter);
        // coord loss (COORD_SCALE = 1)
        float d0 = sx - stx [match];
        float d1 = sy - sty [match];
        float d2 = ow - stw [match];
        float d3 = oh - sth2[match];
        lsum += d0*d0 + d1*d1 + d2*d2 + d3*d3;
        // class CE (CLASS_SCALE * 2)
        int tcl = (int)scls[match];
        float lg[NC];
        float m = -1e30f, ltgt = 0.0f;
        #pragma unroll
        for (int c = 0; c < NC; ++c) {     // static indexing only
            lg[c] = base[(5 + c) * HWSZ];
            m = fmaxf(m, lg[c]);
            if (c == tcl) ltgt = lg[c];
        }
        float se = 0.0f;
        #pragma unroll
        for (int c = 0; c < NC; ++c) se += __expf(lg[c] - m);
        float ce = -(ltgt - m - __logf(se));
        lsum += 2.0f * ce;
    }
    float dc = conf - tconf;
    lsum += cm * dc * dc;

    // block reduction: 64-lane shfl, 4 waves via LDS
    #pragma unroll
    for (int off = 32; off > 0; off >>= 1) lsum += __shfl_down(lsum, off);
    int lane = tid & 63, wid = tid >> 6;
    if (lane == 0) wsum[wid] = lsum;
    __syncthreads();
    if (tid == 0) partials[blockIdx.x] = wsum[0] + wsum[1] + wsum[2] + wsum[3];
}

// Tree-reduce the 1280 block partials -> out[0]. One block, deterministic.
__global__ __launch_bounds__(256) void yolo_reduce(const float* __restrict__ partials,
                                                   float* __restrict__ out)
{
    int tid = threadIdx.x;
    float s = 0.0f;
    #pragma unroll
    for (int i = 0; i < NBLK / 256; ++i) s += partials[i * 256 + tid];
    #pragma unroll
    for (int off = 32; off > 0; off >>= 1) s += __shfl_down(s, off);
    __shared__ float wsum[4];
    int lane = tid & 63, wid = tid >> 6;
    if (lane == 0) wsum[wid] = s;
    __syncthreads();
    if (tid == 0) out[0] = (wsum[0] + wsum[1] + wsum[2] + wsum[3]) * (1.0f / 16.0f);
}

extern "C" void kernel_launch(void* const* d_in, const int* in_sizes, int n_in,
                              void* d_out, int out_size, void* d_ws, size_t ws_size,
                              hipStream_t stream) {
    const float* output   = (const float*)d_in[0];
    const float* target   = (const float*)d_in[1];
    const void*  gt_valid = d_in[2];
    const float* anchors  = (const float*)d_in[3];
    float* out      = (float*)d_out;
    float* partials = (float*)d_ws;    // needs 5120 B; ws is ample

    yolo_loss<<<NBLK, 256, 0, stream>>>(output, target, gt_valid, anchors, partials);
    yolo_reduce<<<1, 256, 0, stream>>>(partials, out);
}